// Round 9
// baseline (422.665 us; speedup 1.0000x reference)
//
#include <hip/hip_runtime.h>
#include <stdint.h>

// Problem: N=8, d=o=16, F=512, NUM_LAYERS=3.  ALL fp32 inputs/outputs.
// out[n,o,g] = LN_o( 0.5*(c1 + c2) )  where
//   c0 = einsum(x, W, A0); h1 = LN_o(c0)
//   c1 = einsum(x, W, A1); c2 = einsum(h1, W, A0)
// einsum(h,W,a)[n,o,g] = sum_{d,f} h[n,d,f] * W[d,f,g,o] * a[f,g]
//
// R0-R8 finding: every fp32 contract variant caps at ~150-160us per 256MB
// W pass (~1.7 TB/s effective), invariant to load width, cols/thread, W/x
// placement, occupancy, and address pattern. R8 (fused 3-kernel, 413us) is
// the best structure. The cap's currency is unknown (bytes vs requests vs
// per-wave serialization) but it is per-pass: so R9 halves pass B's W bytes.
// R9: pass A converts W to fp16 on the fly into Whalf[f][col][d] (write: 2
// coalesced 16B/lane stores per f-iter; W~N(0,1), fp16 rel err 2^-12 ->
// output err ~5e-4, negligible). Pass B reads its 16 d-values as TWO
// contiguous dwordx4 loads per f-iter (2 requests, half bytes): wins ~2x if
// byte-capped, ~8x if request-capped; null (~150us) falsifies both.

#define FC   32    // f's per chunk
#define NCH  16    // 512 / FC

typedef _Float16 h8 __attribute__((ext_vector_type(8)));

// KA: in = x (8,16,512). Writes c0 partials (A0), c1 partials (A1), and
// Whalf[f][col][d] (fp16). grid (16,32), 256 thr, 1 col/thread.
__global__ __launch_bounds__(256)
void k_pass_a(const float* __restrict__ W, const float* __restrict__ A,
              const float* __restrict__ x,
              float* __restrict__ p0, float* __restrict__ p1,
              _Float16* __restrict__ Wh) {
    __shared__ float sx[FC][16][8];   // 16 KB: x slices [f_local][d][n]
    __shared__ float sA0[FC][16];
    __shared__ float sA1[FC][16];

    const int t  = threadIdx.x;       // 0..255
    const int fc = blockIdx.x;        // 0..15
    const int ct = blockIdx.y;        // 0..31
    const int f0 = fc * FC;

    // transpose x slice into LDS (4096 vals, 16/thr); x is 256KB, L2/L3-hot
#pragma unroll
    for (int k = 0; k < 16; ++k) {
        int idx = k * 256 + t;
        int fl = idx >> 7, d = (idx >> 3) & 15, n = idx & 7;
        sx[fl][d][n] = x[n * 8192 + d * 512 + f0 + fl];
    }
#pragma unroll
    for (int k = 0; k < 2; ++k) {
        int idx = k * 256 + t;
        int fl = idx >> 4, gl = idx & 15;
        sA0[fl][gl] = A[(size_t)(f0 + fl) * 512 + ct * 16 + gl];
        sA1[fl][gl] = A[262144 + (size_t)(f0 + fl) * 512 + ct * 16 + gl];
    }
    __syncthreads();

    const int gl  = t >> 4;
    const int o   = t & 15;
    const int col = (ct * 16 + gl) * 16 + o;   // = ct*256 + t
    const float* Wc = W + col;

    float c0[8], c1[8];
#pragma unroll
    for (int n = 0; n < 8; ++n) { c0[n] = 0.f; c1[n] = 0.f; }

    for (int fl = 0; fl < FC; ++fl) {
        const int f = f0 + fl;
        float w[16];
#pragma unroll
        for (int d = 0; d < 16; ++d)
            w[d] = Wc[(size_t)d * 4194304 + (size_t)f * 8192];

        // fp16 conversion store: [f][col][d], 2 x 16B/lane contiguous stores
        {
            h8 lo, hi;
#pragma unroll
            for (int d = 0; d < 8; ++d) { lo[d] = (_Float16)w[d]; hi[d] = (_Float16)w[d + 8]; }
            h8* wp = reinterpret_cast<h8*>(Wh + ((size_t)f * 8192 + col) * 16);
            wp[0] = lo;
            wp[1] = hi;
        }

        float p[8];
#pragma unroll
        for (int n = 0; n < 8; ++n) p[n] = 0.f;
#pragma unroll
        for (int d = 0; d < 16; ++d) {
            float4 xa = *reinterpret_cast<const float4*>(&sx[fl][d][0]);
            float4 xb = *reinterpret_cast<const float4*>(&sx[fl][d][4]);
            p[0] = fmaf(xa.x, w[d], p[0]);
            p[1] = fmaf(xa.y, w[d], p[1]);
            p[2] = fmaf(xa.z, w[d], p[2]);
            p[3] = fmaf(xa.w, w[d], p[3]);
            p[4] = fmaf(xb.x, w[d], p[4]);
            p[5] = fmaf(xb.y, w[d], p[5]);
            p[6] = fmaf(xb.z, w[d], p[6]);
            p[7] = fmaf(xb.w, w[d], p[7]);
        }

        const float a0 = sA0[fl][gl];
        const float a1 = sA1[fl][gl];
#pragma unroll
        for (int n = 0; n < 8; ++n) {
            c0[n] = fmaf(a0, p[n], c0[n]);
            c1[n] = fmaf(a1, p[n], c1[n]);
        }
    }

    size_t base = ((size_t)fc * 8192 + col) * 8;
    float4* dst0 = reinterpret_cast<float4*>(p0 + base);
    dst0[0] = make_float4(c0[0], c0[1], c0[2], c0[3]);
    dst0[1] = make_float4(c0[4], c0[5], c0[6], c0[7]);
    float4* dst1 = reinterpret_cast<float4*>(p1 + base);
    dst1[0] = make_float4(c1[0], c1[1], c1[2], c1[3]);
    dst1[1] = make_float4(c1[4], c1[5], c1[6], c1[7]);
}

// KB: prologue builds h1 rows g'=f0..f0+31 from c0 partials (reduce + LN),
// then contracts against Whalf (fp16, [f][col][d] layout) with A0.
// grid (16,32), 256 thr, 1 col/thread. Writes c2 partials.
__global__ __launch_bounds__(256)
void k_pass_b(const _Float16* __restrict__ Wh, const float* __restrict__ A,
              const float* __restrict__ c0p, float* __restrict__ p2) {
    __shared__ float sx[FC][16][8];   // h1 slices [f_local][d=o][n]
    __shared__ float sA0[FC][16];

    const int t  = threadIdx.x;
    const int fc = blockIdx.x;
    const int ct = blockIdx.y;
    const int f0 = fc * FC;

    // reduce c0 partials over 16 chunks (4096 vals, 16/thr; L2/L3-hot)
#pragma unroll
    for (int k = 0; k < 16; ++k) {
        int idx = k * 256 + t;
        int fl = idx >> 7, o = (idx >> 3) & 15, n = idx & 7;
        float s = 0.f;
#pragma unroll
        for (int ch = 0; ch < NCH; ++ch)
            s += c0p[(((size_t)ch * 512 + f0 + fl) * 16 + o) * 8 + n];
        sx[fl][o][n] = s;
    }
    __syncthreads();
    // LayerNorm over o in place; thread owns (fl,n) -> exclusive column
    {
        int fl = t >> 3, n = t & 7;
        float m = 0.f, v = 0.f;
#pragma unroll
        for (int oo = 0; oo < 16; ++oo) { float y = sx[fl][oo][n]; m += y; v += y * y; }
        m *= (1.f / 16.f);
        v = v * (1.f / 16.f) - m * m;
        float r = rsqrtf(v + 1e-5f);
#pragma unroll
        for (int oo = 0; oo < 16; ++oo) sx[fl][oo][n] = (sx[fl][oo][n] - m) * r;
    }
#pragma unroll
    for (int k = 0; k < 2; ++k) {
        int idx = k * 256 + t;
        int fl = idx >> 4, gl = idx & 15;
        sA0[fl][gl] = A[(size_t)(f0 + fl) * 512 + ct * 16 + gl];
    }
    __syncthreads();

    const int gl  = t >> 4;
    const int col = ct * 256 + t;

    float c2[8];
#pragma unroll
    for (int n = 0; n < 8; ++n) c2[n] = 0.f;

    for (int fl = 0; fl < FC; ++fl) {
        const int f = f0 + fl;
        // 2 contiguous 16B/lane loads: all 16 d-values for this col
        const h8* wp = reinterpret_cast<const h8*>(Wh + ((size_t)f * 8192 + col) * 16);
        h8 lo = wp[0];
        h8 hi = wp[1];
        float w[16];
#pragma unroll
        for (int d = 0; d < 8; ++d) { w[d] = (float)lo[d]; w[d + 8] = (float)hi[d]; }

        float p[8];
#pragma unroll
        for (int n = 0; n < 8; ++n) p[n] = 0.f;
#pragma unroll
        for (int d = 0; d < 16; ++d) {
            float4 xa = *reinterpret_cast<const float4*>(&sx[fl][d][0]);
            float4 xb = *reinterpret_cast<const float4*>(&sx[fl][d][4]);
            p[0] = fmaf(xa.x, w[d], p[0]);
            p[1] = fmaf(xa.y, w[d], p[1]);
            p[2] = fmaf(xa.z, w[d], p[2]);
            p[3] = fmaf(xa.w, w[d], p[3]);
            p[4] = fmaf(xb.x, w[d], p[4]);
            p[5] = fmaf(xb.y, w[d], p[5]);
            p[6] = fmaf(xb.z, w[d], p[6]);
            p[7] = fmaf(xb.w, w[d], p[7]);
        }

        const float a0 = sA0[fl][gl];
#pragma unroll
        for (int n = 0; n < 8; ++n) c2[n] = fmaf(a0, p[n], c2[n]);
    }

    size_t base = ((size_t)fc * 8192 + col) * 8;
    float4* dst = reinterpret_cast<float4*>(p2 + base);
    dst[0] = make_float4(c2[0], c2[1], c2[2], c2[3]);
    dst[1] = make_float4(c2[4], c2[5], c2[6], c2[7]);
}

// KF: y = 0.5*(c1+c2) reduced over 16 chunks, LayerNorm over o, out [n][o][g]
__global__ __launch_bounds__(128)
void k_final(const float* __restrict__ p1, const float* __restrict__ p2,
             float* __restrict__ out) {
    __shared__ float sh[16][8];
    int g = blockIdx.x;                 // 0..511
    int t = threadIdx.x;                // 0..127
    int o = t >> 3, n = t & 7;
    float s0 = 0.f, s1 = 0.f;
#pragma unroll
    for (int ch = 0; ch < NCH; ++ch) {
        size_t idx = (((size_t)ch * 512 + g) * 16 + o) * 8 + n;
        s0 += p1[idx];
        s1 += p2[idx];
    }
    float s = 0.5f * (s0 + s1);
    sh[o][n] = s;
    __syncthreads();
    float m = 0.f, v = 0.f;
#pragma unroll
    for (int oo = 0; oo < 16; ++oo) { float y = sh[oo][n]; m += y; v += y * y; }
    m *= (1.f / 16.f);
    v = v * (1.f / 16.f) - m * m;
    float r = rsqrtf(v + 1e-5f);
    out[n * 8192 + o * 512 + g] = (s - m) * r;
}

extern "C" void kernel_launch(void* const* d_in, const int* in_sizes, int n_in,
                              void* d_out, int out_size, void* d_ws, size_t ws_size,
                              hipStream_t stream) {
    const float* x = (const float*)d_in[0];   // (8,16,512)      fp32
    const float* W = (const float*)d_in[1];   // (16,512,512,16) fp32
    const float* A = (const float*)d_in[2];   // (2,512,512)     fp32
    float* out = (float*)d_out;               // (8,16,512)      fp32

    float* ws  = (float*)d_ws;
    float* c0p = ws;                    // 1048576 floats: c0 partials [16][8192][8]
    float* c1p = c0p + 1048576;         // 1048576 floats: c1 partials
    float* c2p = c1p + 1048576;         // 1048576 floats: c2 partials
    _Float16* Wh = (_Float16*)(c2p + 1048576);  // 67108864 halfs: W fp16 [f][col][d] (128 MB)
    // total ws use: 140 MB

    k_pass_a<<<dim3(NCH, 32), 256, 0, stream>>>(W, A, x, c0p, c1p, Wh);
    k_pass_b<<<dim3(NCH, 32), 256, 0, stream>>>(Wh, A, c0p, c2p);
    k_final<<<512, 128, 0, stream>>>(c1p, c2p, out);
}